// Round 5
// baseline (435.733 us; speedup 1.0000x reference)
//
#include <hip/hip_runtime.h>
#include <hip/hip_cooperative_groups.h>

namespace cg = cooperative_groups;

// AdaIN on MI355X.
// content: (Nc=1e6, C=64) f32, style: (Ns=2.5e5, C=64) f32, B=16 segments.
// Primary path: single cooperative kernel (zero ws -> reduce -> finalize ->
// apply with grid.sync between phases). Fallback path (if cooperative launch
// is refused): the proven 4-dispatch chain. Identical math on both paths.

#define NB 16          // num_batches
#define NC 64          // channels (== wavefront size)
#define NREP 16        // global partial-buffer replicas

typedef float fvec4 __attribute__((ext_vector_type(4)));   // nontemporal-ok

// ws float layout:
#define WS_CPART 0                        // NREP * 2048 (sum[1024], sumsq[1024])
#define WS_SPART (NREP * 2048)            // NREP * 2048
#define WS_CCNT  (2 * NREP * 2048)        // NREP * 16
#define WS_SCNT  (WS_CCNT + NREP * NB)    // NREP * 16
#define WS_SCALE (WS_SCNT + NREP * NB)    // 1024
#define WS_BIAS  (WS_SCALE + 1024)        // 1024
#define WS_ZERO_FLOATS WS_SCALE

__device__ __forceinline__ void acc16(int b, float v, float* s, float* q)
{
    // b is wave-uniform (readfirstlane'd) -> scalar branch tree, no divergence.
    switch (b) {
#define K(k) case k: s[k] += v; q[k] = fmaf(v, v, q[k]); break;
        K(0) K(1) K(2)  K(3)  K(4)  K(5)  K(6)  K(7)
        K(8) K(9) K(10) K(11) K(12) K(13) K(14) K(15)
#undef K
        default: break;
    }
}

// ---- shared phase bodies ----------------------------------------------------

__device__ __forceinline__ void reduce_body(
    const float* __restrict__ feats, const int* __restrict__ idx, int n,
    float* __restrict__ part, float* __restrict__ cntp,
    int blk, int nblk, int tid, float* red /*4*NB*NC LDS*/)
{
    const int lane = tid & 63;
    const int wv   = tid >> 6;

    const int W  = nblk * 4;
    const int w  = blk * 4 + wv;
    const int L  = (n + W - 1) / W;
    const int r0 = w * L;
    const int r1 = (r0 + L < n) ? (r0 + L) : n;

    float s[NB], q[NB];
    #pragma unroll
    for (int k = 0; k < NB; ++k) { s[k] = 0.f; q[k] = 0.f; }
    float cnt = 0.f;                       // lane b holds count of batch b

    const float* p = feats + (size_t)r0 * NC + lane;
    int r = r0;
    for (; r + 4 <= r1; r += 4, p += 4 * NC) {
        const float v0 = p[0];
        const float v1 = p[NC];
        const float v2 = p[2 * NC];
        const float v3 = p[3 * NC];
        const int b0 = __builtin_amdgcn_readfirstlane(idx[r + 0]);
        const int b1 = __builtin_amdgcn_readfirstlane(idx[r + 1]);
        const int b2 = __builtin_amdgcn_readfirstlane(idx[r + 2]);
        const int b3 = __builtin_amdgcn_readfirstlane(idx[r + 3]);
        acc16(b0, v0, s, q); cnt += (lane == b0) ? 1.f : 0.f;
        acc16(b1, v1, s, q); cnt += (lane == b1) ? 1.f : 0.f;
        acc16(b2, v2, s, q); cnt += (lane == b2) ? 1.f : 0.f;
        acc16(b3, v3, s, q); cnt += (lane == b3) ? 1.f : 0.f;
    }
    for (; r < r1; ++r, p += NC) {
        const float v = p[0];
        const int  b = __builtin_amdgcn_readfirstlane(idx[r]);
        acc16(b, v, s, q); cnt += (lane == b) ? 1.f : 0.f;
    }

    float* dst = part + (blk & (NREP - 1)) * 2048;

    #pragma unroll
    for (int k = 0; k < NB; ++k) red[wv * 1024 + k * NC + lane] = s[k];
    __syncthreads();
    for (int i = tid; i < NB * NC; i += 256)
        atomicAdd(&dst[i], red[i] + red[1024 + i] + red[2048 + i] + red[3072 + i]);
    __syncthreads();
    #pragma unroll
    for (int k = 0; k < NB; ++k) red[wv * 1024 + k * NC + lane] = q[k];
    __syncthreads();
    for (int i = tid; i < NB * NC; i += 256)
        atomicAdd(&dst[1024 + i], red[i] + red[1024 + i] + red[2048 + i] + red[3072 + i]);

    if (lane < NB)
        atomicAdd(&cntp[(blk & (NREP - 1)) * NB + lane], cnt);
}

__device__ __forceinline__ void finalize_body(float* __restrict__ ws, int c)
{
    const float* c_part = ws + WS_CPART;
    const float* s_part = ws + WS_SPART;
    const float* c_cntp = ws + WS_CCNT;
    const float* s_cntp = ws + WS_SCNT;
    float* scale = ws + WS_SCALE;
    float* bias  = ws + WS_BIAS;

    float gm = 0.f, gs = 0.f;
    for (int b = 0; b < NB; ++b) {
        float csum = 0.f, csq = 0.f, ssum = 0.f, ssq = 0.f, ccnt = 0.f, scnt = 0.f;
        #pragma unroll
        for (int rep = 0; rep < NREP; ++rep) {
            csum += c_part[rep * 2048 + b * NC + c];
            csq  += c_part[rep * 2048 + 1024 + b * NC + c];
            ssum += s_part[rep * 2048 + b * NC + c];
            ssq  += s_part[rep * 2048 + 1024 + b * NC + c];
            ccnt += c_cntp[rep * NB + b];
            scnt += s_cntp[rep * NB + b];
        }
        const float smean = ssum / scnt;
        const float svar  = (ssq - scnt * smean * smean) / (scnt - 1.0f);
        const float sstd  = sqrtf(fmaxf(svar, 0.f)) + 1e-8f;
        if (b == 0) { gm = smean; gs = sstd; }
        else        { gm = 0.9f * gm + 0.1f * smean; gs = 0.9f * gs + 0.1f * sstd; }
        const float cmean = csum / ccnt;
        const float cvar  = (csq - ccnt * cmean * cmean) / (ccnt - 1.0f);
        const float cstd  = sqrtf(fmaxf(cvar, 0.f)) + 1e-8f;
        const float sc = gs / cstd;        // out = sc*x + bi
        scale[b * NC + c] = sc;
        bias [b * NC + c] = gm - sc * cmean;
    }
}

__device__ __forceinline__ void apply_body(
    const float* __restrict__ content, const int* __restrict__ ci, int Nc,
    const float* __restrict__ ws, fvec4* __restrict__ out4,
    int gid, int gsize, int tid, float* red /*>= 2*NB*17*4 floats LDS*/)
{
    fvec4* s_sc = (fvec4*)red;                 // NB*17 fvec4, stride-17 pad
    fvec4* s_bi = (fvec4*)(red + NB * 17 * 4);
    const fvec4* scale4 = (const fvec4*)(ws + WS_SCALE);
    const fvec4* bias4  = (const fvec4*)(ws + WS_BIAS);
    for (int i = tid; i < NB * 16; i += 256) {
        const int b = i >> 4, c4 = i & 15;
        s_sc[b * 17 + c4] = scale4[i];
        s_bi[b * 17 + c4] = bias4[i];
    }
    __syncthreads();

    const fvec4* feats4 = (const fvec4*)content;
    const int total4 = Nc * 16;
    const int stride = gsize * 256;
    for (int i = gid * 256 + tid; i < total4; i += stride) {
        const int r  = i >> 4;
        const int c4 = i & 15;
        const int b  = ci[r];
        const fvec4 v  = feats4[i];
        const fvec4 sc = s_sc[b * 17 + c4];
        const fvec4 bi = s_bi[b * 17 + c4];
        fvec4 o;
        o.x = fmaf(sc.x, v.x, bi.x);
        o.y = fmaf(sc.y, v.y, bi.y);
        o.z = fmaf(sc.z, v.z, bi.z);
        o.w = fmaf(sc.w, v.w, bi.w);
        __builtin_nontemporal_store(o, &out4[i]);
    }
}

// ---- primary: single cooperative kernel -------------------------------------

__global__ __launch_bounds__(256, 4) void adain_fused(
    const float* __restrict__ content, const int* __restrict__ ci, int Nc,
    const float* __restrict__ style,   const int* __restrict__ si, int Ns,
    float* __restrict__ ws, fvec4* __restrict__ out4)
{
    cg::grid_group grid = cg::this_grid();
    const int tid = threadIdx.x;
    const int bid = blockIdx.x;
    const int G   = gridDim.x;

    __shared__ float red[4 * NB * NC];     // 16 KB, reused across phases

    // Phase 0: zero accumulators (ws poisoned 0xAA, never re-poisoned).
    for (int i = bid * 256 + tid; i < WS_ZERO_FLOATS; i += G * 256)
        ws[i] = 0.f;
    grid.sync();

    // Phase 1: segment reduce (content blocks [0,CBn), style [CBn,G)).
    {
        const int CBn = (G * 4) / 5;       // 4:1 split matches Nc:Ns
        if (bid < CBn)
            reduce_body(content, ci, Nc, ws + WS_CPART, ws + WS_CCNT,
                        bid, CBn, tid, red);
        else
            reduce_body(style, si, Ns, ws + WS_SPART, ws + WS_SCNT,
                        bid - CBn, G - CBn, tid, red);
    }
    grid.sync();

    // Phase 2: finalize (block 0, thread c = channel).
    if (bid == 0 && tid < NC)
        finalize_body(ws, tid);
    grid.sync();

    // Phase 3: apply.
    apply_body(content, ci, Nc, ws, out4, bid, G, tid, red);
}

// ---- fallback: proven 4-dispatch chain ---------------------------------------

#define FB_CBLKS 2048
#define FB_SBLKS 512

__global__ __launch_bounds__(256) void reduce_stats_fb(
    const float* __restrict__ content, const int* __restrict__ ci, int Nc,
    const float* __restrict__ style,   const int* __restrict__ si, int Ns,
    float* __restrict__ ws)
{
    __shared__ float red[4 * NB * NC];
    if (blockIdx.x < FB_CBLKS)
        reduce_body(content, ci, Nc, ws + WS_CPART, ws + WS_CCNT,
                    blockIdx.x, FB_CBLKS, threadIdx.x, red);
    else
        reduce_body(style, si, Ns, ws + WS_SPART, ws + WS_SCNT,
                    blockIdx.x - FB_CBLKS, FB_SBLKS, threadIdx.x, red);
}

__global__ void finalize_fb(float* __restrict__ ws)
{
    if (threadIdx.x < NC) finalize_body(ws, threadIdx.x);
}

__global__ __launch_bounds__(256) void apply_fb(
    const float* __restrict__ content, const int* __restrict__ ci, int Nc,
    const float* __restrict__ ws, fvec4* __restrict__ out4)
{
    __shared__ float red[2 * NB * 17 * 4];
    apply_body(content, ci, Nc, ws, out4, blockIdx.x, gridDim.x, threadIdx.x, red);
}

// ---- launcher ----------------------------------------------------------------

extern "C" void kernel_launch(void* const* d_in, const int* in_sizes, int n_in,
                              void* d_out, int out_size, void* d_ws, size_t ws_size,
                              hipStream_t stream)
{
    const float* content = (const float*)d_in[0];
    const float* style   = (const float*)d_in[1];
    const int*   ci      = (const int*)d_in[2];
    const int*   si      = (const int*)d_in[3];

    int Nc = in_sizes[0] / NC;   // 1,000,000
    int Ns = in_sizes[1] / NC;   //   250,000

    float* ws = (float*)d_ws;
    fvec4* out4 = (fvec4*)d_out;

    // Size the cooperative grid from the runtime's own occupancy answer.
    hipError_t lerr = hipErrorUnknown;
    int occ = 0;
    hipError_t oerr = hipOccupancyMaxActiveBlocksPerMultiprocessor(
        &occ, (const void*)adain_fused, 256, 0);
    if (oerr == hipSuccess && occ > 0) {
        int grid = occ * 256;              // 256 CUs on MI355X
        if (grid > 1024) grid = 1024;      // 4 blocks/CU is plenty for BW
        void* args[] = { (void*)&content, (void*)&ci, (void*)&Nc,
                         (void*)&style,   (void*)&si, (void*)&Ns,
                         (void*)&ws, (void*)&out4 };
        lerr = hipLaunchCooperativeKernel((const void*)adain_fused,
                                          dim3(grid), dim3(256), args, 0, stream);
    }

    if (lerr != hipSuccess) {
        // Fallback: proven multi-dispatch path (identical math).
        (void)hipMemsetAsync(ws, 0, WS_ZERO_FLOATS * sizeof(float), stream);
        reduce_stats_fb<<<FB_CBLKS + FB_SBLKS, 256, 0, stream>>>(
            content, ci, Nc, style, si, Ns, ws);
        finalize_fb<<<1, 64, 0, stream>>>(ws);
        apply_fb<<<2048, 256, 0, stream>>>(content, ci, Nc, ws, out4);
    }
}

// Round 6
// 233.736 us; speedup vs baseline: 1.8642x; 1.8642x over previous
//
#include <hip/hip_runtime.h>

// AdaIN on MI355X — 4-dispatch pipeline (coop abandoned: R5 showed it halves
// occupancy and doubles latency-bound phase time).
// content: (Nc=1e6, C=64) f32, style: (Ns=2.5e5, C=64) f32, B=16 segments.
// memset ws -> reduce (8-row double-buffered register accumulators) ->
// finalize (EMA scan, fused scale/bias) -> apply (out = sc[b]*x + bi[b]).

#define NB 16          // num_batches
#define NC 64          // channels (== wavefront size)
#define NREP 16        // global partial-buffer replicas
#define CBLKS 4096     // content-reduce blocks (16384 waves, L=62)
#define SBLKS 1024     // style-reduce blocks   (4096 waves,  L=62)

typedef float fvec4 __attribute__((ext_vector_type(4)));   // nontemporal-ok

// ws float layout:
#define WS_CPART 0                        // NREP * 2048 (sum[1024], sumsq[1024])
#define WS_SPART (NREP * 2048)            // NREP * 2048
#define WS_CCNT  (2 * NREP * 2048)        // NREP * 16
#define WS_SCNT  (WS_CCNT + NREP * NB)    // NREP * 16
#define WS_SCALE (WS_SCNT + NREP * NB)    // 1024
#define WS_BIAS  (WS_SCALE + 1024)        // 1024
#define WS_ZERO_FLOATS WS_SCALE

__device__ __forceinline__ void acc16(int b, float v, float* s, float* q)
{
    // b is wave-uniform (readfirstlane'd) -> scalar branch tree, no divergence.
    switch (b) {
#define K(k) case k: s[k] += v; q[k] = fmaf(v, v, q[k]); break;
        K(0) K(1) K(2)  K(3)  K(4)  K(5)  K(6)  K(7)
        K(8) K(9) K(10) K(11) K(12) K(13) K(14) K(15)
#undef K
        default: break;
    }
}

__device__ __forceinline__ void reduce_body(
    const float* __restrict__ feats, const int* __restrict__ idx, int n,
    float* __restrict__ part, float* __restrict__ cntp,
    int blk, int nblk, int tid, float* red /*4*NB*NC LDS*/)
{
    const int lane = tid & 63;
    const int wv   = tid >> 6;

    const int W  = nblk * 4;
    const int w  = blk * 4 + wv;
    const int L  = (n + W - 1) / W;
    const int r0 = w * L;
    const int r1 = (r0 + L < n) ? (r0 + L) : n;
    const int len = r1 - r0;

    float s[NB], q[NB];
    #pragma unroll
    for (int k = 0; k < NB; ++k) { s[k] = 0.f; q[k] = 0.f; }
    float cnt = 0.f;                       // lane b holds count of batch b

// batch-load 8 rows (full-group fast path: constant byte offsets)
#define LOAD8F(V, I, pp, rr) \
    _Pragma("unroll") for (int j = 0; j < 8; ++j) { \
        V[j] = (pp)[j * NC]; I[j] = idx[(rr) + j]; }
// clamped load for the (single) partial group
#define LOAD8C(V, I, rr) \
    _Pragma("unroll") for (int j = 0; j < 8; ++j) { \
        int rc = (rr) + j; rc = (rc < r1) ? rc : (r1 - 1); \
        V[j] = feats[(size_t)rc * NC + lane]; I[j] = idx[rc]; }
// process 8 rows, no guard (group known full)
#define PROC8F(V, I) \
    _Pragma("unroll") for (int j = 0; j < 8; ++j) { \
        const int b = __builtin_amdgcn_readfirstlane(I[j]); \
        acc16(b, V[j], s, q); cnt += (lane == b) ? 1.f : 0.f; }
// process 8 rows with wave-uniform validity guard (last group)
#define PROC8G(V, I, rr) \
    _Pragma("unroll") for (int j = 0; j < 8; ++j) { \
        if ((rr) + j < r1) { \
            const int b = __builtin_amdgcn_readfirstlane(I[j]); \
            acc16(b, V[j], s, q); cnt += (lane == b) ? 1.f : 0.f; } }

    if (len > 0) {
        float vA[8], vB[8]; int iA[8], iB[8];
        const float* p = feats + (size_t)r0 * NC + lane;
        int r = r0;
        const int ngrp = (len + 7) >> 3;
        if (ngrp == 1) {
            LOAD8C(vA, iA, r);
            PROC8G(vA, iA, r);
        } else {
            LOAD8F(vA, iA, p, r);          // group 0 is full
            for (int g = 1; g < ngrp; ++g) {
                const float* pn = p + 8 * NC;
                const int rn = r + 8;
                if (len - 8 * g >= 8) { LOAD8F(vB, iB, pn, rn); }
                else                  { LOAD8C(vB, iB, rn); }
                PROC8F(vA, iA);            // overlap with B's loads in flight
                #pragma unroll
                for (int j = 0; j < 8; ++j) { vA[j] = vB[j]; iA[j] = iB[j]; }
                p = pn; r = rn;
            }
            PROC8G(vA, iA, r);             // last group (may be partial)
        }
    }
#undef LOAD8F
#undef LOAD8C
#undef PROC8F
#undef PROC8G

    // Cross-wave reduce in LDS (two phases reuse the buffer), then one
    // atomicAdd per (b,c) per block into this block's replica.
    float* dst = part + (blk & (NREP - 1)) * 2048;

    #pragma unroll
    for (int k = 0; k < NB; ++k) red[wv * 1024 + k * NC + lane] = s[k];
    __syncthreads();
    for (int i = tid; i < NB * NC; i += 256)
        atomicAdd(&dst[i], red[i] + red[1024 + i] + red[2048 + i] + red[3072 + i]);
    __syncthreads();
    #pragma unroll
    for (int k = 0; k < NB; ++k) red[wv * 1024 + k * NC + lane] = q[k];
    __syncthreads();
    for (int i = tid; i < NB * NC; i += 256)
        atomicAdd(&dst[1024 + i], red[i] + red[1024 + i] + red[2048 + i] + red[3072 + i]);

    if (lane < NB)
        atomicAdd(&cntp[(blk & (NREP - 1)) * NB + lane], cnt);
}

__global__ __launch_bounds__(256) void reduce_stats(
    const float* __restrict__ content, const int* __restrict__ ci, int Nc,
    const float* __restrict__ style,   const int* __restrict__ si, int Ns,
    float* __restrict__ ws)
{
    __shared__ float red[4 * NB * NC];
    if (blockIdx.x < CBLKS)
        reduce_body(content, ci, Nc, ws + WS_CPART, ws + WS_CCNT,
                    blockIdx.x, CBLKS, threadIdx.x, red);
    else
        reduce_body(style, si, Ns, ws + WS_SPART, ws + WS_SCNT,
                    blockIdx.x - CBLKS, SBLKS, threadIdx.x, red);
}

__global__ void finalize_kernel(float* __restrict__ ws)
{
    if (threadIdx.x >= NC) return;
    const int c = threadIdx.x;
    const float* c_part = ws + WS_CPART;
    const float* s_part = ws + WS_SPART;
    const float* c_cntp = ws + WS_CCNT;
    const float* s_cntp = ws + WS_SCNT;
    float* scale = ws + WS_SCALE;
    float* bias  = ws + WS_BIAS;

    float gm = 0.f, gs = 0.f;
    for (int b = 0; b < NB; ++b) {
        float csum = 0.f, csq = 0.f, ssum = 0.f, ssq = 0.f, ccnt = 0.f, scnt = 0.f;
        #pragma unroll
        for (int rep = 0; rep < NREP; ++rep) {
            csum += c_part[rep * 2048 + b * NC + c];
            csq  += c_part[rep * 2048 + 1024 + b * NC + c];
            ssum += s_part[rep * 2048 + b * NC + c];
            ssq  += s_part[rep * 2048 + 1024 + b * NC + c];
            ccnt += c_cntp[rep * NB + b];
            scnt += s_cntp[rep * NB + b];
        }
        const float smean = ssum / scnt;
        const float svar  = (ssq - scnt * smean * smean) / (scnt - 1.0f);
        const float sstd  = sqrtf(fmaxf(svar, 0.f)) + 1e-8f;
        if (b == 0) { gm = smean; gs = sstd; }
        else        { gm = 0.9f * gm + 0.1f * smean; gs = 0.9f * gs + 0.1f * sstd; }
        const float cmean = csum / ccnt;
        const float cvar  = (csq - ccnt * cmean * cmean) / (ccnt - 1.0f);
        const float cstd  = sqrtf(fmaxf(cvar, 0.f)) + 1e-8f;
        const float sc = gs / cstd;        // out = sc*x + bi
        scale[b * NC + c] = sc;
        bias [b * NC + c] = gm - sc * cmean;
    }
}

__global__ __launch_bounds__(256) void apply_kernel(
    const float* __restrict__ content, const int* __restrict__ ci, int Nc,
    const float* __restrict__ ws, fvec4* __restrict__ out4)
{
    __shared__ fvec4 s_sc[NB * 17];        // stride-17 pad
    __shared__ fvec4 s_bi[NB * 17];
    const fvec4* scale4 = (const fvec4*)(ws + WS_SCALE);
    const fvec4* bias4  = (const fvec4*)(ws + WS_BIAS);
    for (int i = threadIdx.x; i < NB * 16; i += 256) {
        const int b = i >> 4, c4 = i & 15;
        s_sc[b * 17 + c4] = scale4[i];
        s_bi[b * 17 + c4] = bias4[i];
    }
    __syncthreads();

    const fvec4* feats4 = (const fvec4*)content;
    const int total4 = Nc * 16;
    const int stride = gridDim.x * 256;
    for (int i = blockIdx.x * 256 + threadIdx.x; i < total4; i += stride) {
        const int r  = i >> 4;
        const int c4 = i & 15;
        const int b  = ci[r];
        const fvec4 v  = feats4[i];
        const fvec4 sc = s_sc[b * 17 + c4];
        const fvec4 bi = s_bi[b * 17 + c4];
        fvec4 o;
        o.x = fmaf(sc.x, v.x, bi.x);
        o.y = fmaf(sc.y, v.y, bi.y);
        o.z = fmaf(sc.z, v.z, bi.z);
        o.w = fmaf(sc.w, v.w, bi.w);
        __builtin_nontemporal_store(o, &out4[i]);
    }
}

extern "C" void kernel_launch(void* const* d_in, const int* in_sizes, int n_in,
                              void* d_out, int out_size, void* d_ws, size_t ws_size,
                              hipStream_t stream)
{
    const float* content = (const float*)d_in[0];
    const float* style   = (const float*)d_in[1];
    const int*   ci      = (const int*)d_in[2];
    const int*   si      = (const int*)d_in[3];

    const int Nc = in_sizes[0] / NC;   // 1,000,000
    const int Ns = in_sizes[1] / NC;   //   250,000

    float* ws = (float*)d_ws;
    // ws never re-poisoned between replays: zero accumulators every call.
    (void)hipMemsetAsync(ws, 0, WS_ZERO_FLOATS * sizeof(float), stream);

    reduce_stats<<<CBLKS + SBLKS, 256, 0, stream>>>(content, ci, Nc, style, si, Ns, ws);
    finalize_kernel<<<1, 64, 0, stream>>>(ws);
    apply_kernel<<<4096, 256, 0, stream>>>(content, ci, Nc, ws, (fvec4*)d_out);
}